// Round 4
// baseline (14422.050 us; speedup 1.0000x reference)
//
#include <hip/hip_runtime.h>
#include <cstdint>
#include <cstddef>

#define BB 32
#define NN 256
#define PP 3072
#define NG 192   // pixel groups of 16
#define RING 16

// ---- init: gamma0 = tanh(x @ W_init) fp64, ring[0]=theta0, zero state ----
__global__ __launch_bounds__(256) void k_init(
    const float* __restrict__ x, const float* __restrict__ theta0,
    const float* __restrict__ W_init, double* __restrict__ ring,
    double* __restrict__ gamma_g, double* __restrict__ memD,
    double* __restrict__ a_g, float* __restrict__ rate,
    unsigned short* __restrict__ maskA, unsigned short* __restrict__ maskB) {
  const int blk = blockIdx.x, tid = threadIdx.x;
  if (blk < BB) {
    __shared__ double xl[PP];  // 24 KB
    for (int i = tid; i < PP; i += 256) xl[i] = (double)x[(size_t)blk * PP + i];
    __syncthreads();
    double acc = 0.0;
    for (int p = 0; p < PP; ++p)
      acc += xl[p] * (double)W_init[(size_t)p * NN + tid];
    gamma_g[blk * NN + tid] = tanh(acc);
    ring[blk * NN + tid] = (double)theta0[blk * NN + tid];
  } else {
    const int i0 = (blk - BB) * 256 + tid, st = (gridDim.x - BB) * 256;
    for (int i = i0; i < BB * PP; i += st) { memD[i] = 0.0; rate[i] = 0.f; }
    for (int i = i0; i < BB * NN; i += st) a_g[i] = 0.0;
    for (int i = i0; i < BB * NG; i += st) { maskA[i] = 0; maskB[i] = 0; }
  }
}

// ---- spike update (s = 5k+1), pure VALU fp64 — NO MFMA ----
// Spike state lives as bitmasks: mask[b*NG+w] bit i = spike of pixel w*16+i.
// cur = gate@W_gate + 0.1*(spk@W_rec)  (spk@W_rec = sparse sum of rows,
// every term an exact fp32 value; fp64 accumulation is order-robust).
// mem = 0.9*mem*(1-spk_old) + cur; spk = (mem-1 > 0).
// Block = 16 pixels x 32 batches = 512 threads, one output each.
__global__ __launch_bounds__(512) void k_spike(
    const unsigned short* __restrict__ mask_rd,
    unsigned short* __restrict__ mask_wr, double* __restrict__ memD,
    const double* __restrict__ gateT, const float* __restrict__ W_rec,
    const float* __restrict__ W_gate, float* __restrict__ rate, int accum) {
  const int g = blockIdx.x, j0 = g * 16;
  const int tid = threadIdx.x;
  const int pi = tid & 15, b = tid >> 4;  // pixel-in-group, batch
  const int p = j0 + pi;

  // rec part: sparse over previous-update spikes
  double vr = 0.0;
  for (int w = 0; w < NG; ++w) {
    unsigned int m = mask_rd[b * NG + w];
    while (m) {
      int bit = __builtin_ctz(m);
      m &= m - 1;
      vr += (double)W_rec[(size_t)(w * 16 + bit) * PP + p];
    }
  }
  // gate part: dense K=256 fp64
  double vg = 0.0;
  for (int k = 0; k < NN; ++k)
    vg += gateT[k * BB + b] * (double)W_gate[(size_t)k * PP + p];

  const double cur = vg + 0.1 * vr;
  const double so = (double)((mask_rd[b * NG + g] >> pi) & 1);
  const size_t idx = (size_t)b * PP + p;
  const double mv = 0.9 * memD[idx] * (1.0 - so) + cur;
  const double sv = (mv - 1.0 > 0.0) ? 1.0 : 0.0;
  memD[idx] = mv;
  if (accum) rate[idx] += (float)sv;

  // new mask: wave = 4 batches x 16 pixels; bits [16*bl .. 16*bl+15] of the
  // ballot are (batch wb+bl, pixels 0..15)
  unsigned long long bal = __ballot(sv > 0.5);
  const int lane = tid & 63;
  const int bl = lane >> 4;
  const int wb = (tid >> 6) * 4;
  if ((lane & 15) == 0)
    mask_wr[(wb + bl) * NG + g] =
        (unsigned short)((bal >> (16 * bl)) & 0xFFFFull);
}

// ---- theta steps s0..s1 (fp64) + a = tanh(spk@W_fb) + gamma/gate ----
__global__ __launch_bounds__(512) void k_theta(
    double* __restrict__ ring, double* __restrict__ gamma_g,
    double* __restrict__ a_g, double* __restrict__ gateT,
    const unsigned short* __restrict__ spk_mask,
    const float* __restrict__ omega, const float* __restrict__ W_ro,
    const float* __restrict__ W_fb, int s0, int s1, int has_spike) {
  const int b = blockIdx.x, tid = threadIdx.x;
  const int j = tid & 255, half = tid >> 8;
  __shared__ double acc_half[256];
  __shared__ double red[32];
  __shared__ double th[256];

  // a-matmul: sparse over the NEW spike bitmask (written by k_spike)
  double acc = 0.0;
  if (has_spike) {
    for (int w = half * 96; w < half * 96 + 96; ++w) {
      unsigned int m = spk_mask[b * NG + w];
      while (m) {
        int bit = __builtin_ctz(m);
        m &= m - 1;
        acc += (double)W_fb[(size_t)(w * 16 + bit) * NN + j];
      }
    }
  }
  if (half) acc_half[j] = acc;
  __syncthreads();
  double new_a = 0.0;
  if (!half && has_spike) new_a = tanh(acc + acc_half[j]);

  double t = 0.0, aj = 0.0, gm = 0.0, om = 0.0;
  if (tid < 256) {
    t = ring[((s0 - 1) & (RING - 1)) * BB * NN + b * NN + j];
    aj = a_g[b * NN + j];
    gm = gamma_g[b * NN + j];
    om = (double)omega[j];
  }
  const int lane = tid & 63, wid = tid >> 6;
  for (int s = s0; s <= s1; ++s) {
    // step s0 (=5k+1) uses the OLD a (ref: spike update follows theta update)
    if (tid < 256 && has_spike && s == s0 + 1) {
      aj = new_a;
      a_g[b * NN + j] = aj;
    }
    double sn = 0.0, cs = 0.0;
    if (tid < 256) sincos(t, &sn, &cs);
    double r0 = sn, r1 = cs, r2 = aj * sn, r3 = aj * cs;
#pragma unroll
    for (int o = 32; o; o >>= 1) {
      r0 += __shfl_down(r0, o);
      r1 += __shfl_down(r1, o);
      r2 += __shfl_down(r2, o);
      r3 += __shfl_down(r3, o);
    }
    if (lane == 0) {
      red[wid * 4 + 0] = r0;
      red[wid * 4 + 1] = r1;
      red[wid * 4 + 2] = r2;
      red[wid * 4 + 3] = r3;
    }
    __syncthreads();
    double S = red[0] + red[4] + red[8] + red[12];
    double C = red[1] + red[5] + red[9] + red[13];
    double AS = red[2] + red[6] + red[10] + red[14];
    double AC = red[3] + red[7] + red[11] + red[15];
    __syncthreads();
    if (tid < 256) {
      double base = cs * S - sn * C;
      double wgt = 0.5 * (cs * aj * AS - sn * aj * AC);
      double dth = om + (1.0 / 256.0) * (base + wgt) + 0.5 * gm;
      t = t + 0.1 * dth;
      ring[(s & (RING - 1)) * BB * NN + b * NN + j] = t;
    }
  }
  if (tid < 256) th[j] = t;
  __syncthreads();
  if (tid < 256) {
    double acc2 = 0.0;
    for (int i = 0; i < NN; ++i) acc2 += th[i] * (double)W_ro[i * NN + j];
    double gnew = tanh(acc2);
    gamma_g[b * NN + j] = gnew;
    int sd = s1 - 11;
    if (sd < 0) sd = 0;
    double dly = ring[(sd & (RING - 1)) * BB * NN + b * NN + j];
    double gt = gnew * 0.5 * (1.0 + cos(t - dly));
    gateT[j * BB + b] = gt;  // [osc][batch]
  }
}

// ---- classifier: logits = (rate/30) @ W_cls + b_cls, fp64 accumulate ----
__global__ __launch_bounds__(256) void k_cls(const float* __restrict__ rate,
                                             const float* __restrict__ Wcls,
                                             const float* __restrict__ bcls,
                                             float* __restrict__ out) {
  const int b = blockIdx.x, t = threadIdx.x;
  double acc[10];
#pragma unroll
  for (int c = 0; c < 10; ++c) acc[c] = 0.0;
  for (int p = t; p < PP; p += 256) {
    double r = (double)rate[(size_t)b * PP + p] / 30.0;
#pragma unroll
    for (int c = 0; c < 10; ++c) acc[c] += r * (double)Wcls[(size_t)p * 10 + c];
  }
  __shared__ double sh[10][256];  // 20 KB
#pragma unroll
  for (int c = 0; c < 10; ++c) sh[c][t] = acc[c];
  __syncthreads();
  for (int off = 128; off; off >>= 1) {
    if (t < off)
#pragma unroll
      for (int c = 0; c < 10; ++c) sh[c][t] += sh[c][t + off];
    __syncthreads();
  }
  if (t < 10) out[b * 10 + t] = (float)(sh[t][0] + (double)bcls[t]);
}

extern "C" void kernel_launch(void* const* d_in, const int* in_sizes, int n_in,
                              void* d_out, int out_size, void* d_ws,
                              size_t ws_size, hipStream_t stream) {
  const float* x = (const float*)d_in[0];
  const float* theta0 = (const float*)d_in[1];
  const float* W_init = (const float*)d_in[2];
  const float* omega = (const float*)d_in[3];
  const float* W_ro = (const float*)d_in[4];
  const float* W_gate = (const float*)d_in[5];
  const float* W_rec = (const float*)d_in[6];
  const float* W_fb = (const float*)d_in[7];
  const float* W_cls = (const float*)d_in[8];
  const float* b_cls = (const float*)d_in[9];

  char* w = (char*)d_ws;
  size_t off = 0;
  auto alloc = [&](size_t sz) -> void* {
    void* p = w + off;
    off = (off + sz + 255) & ~(size_t)255;
    return p;
  };
  double* ring = (double*)alloc((size_t)RING * BB * NN * 8);  // theta ring
  double* gamma = (double*)alloc((size_t)BB * NN * 8);
  double* a_g = (double*)alloc((size_t)BB * NN * 8);
  double* gateT = (double*)alloc((size_t)BB * NN * 8);
  double* memD = (double*)alloc((size_t)BB * PP * 8);
  float* rate = (float*)alloc((size_t)BB * PP * 4);
  unsigned short* maskA = (unsigned short*)alloc((size_t)BB * NG * 2);
  unsigned short* maskB = (unsigned short*)alloc((size_t)BB * NG * 2);
  // total ~2.3 MB of ws

  k_init<<<224, 256, 0, stream>>>(x, theta0, W_init, ring, gamma, memD, a_g,
                                  rate, maskA, maskB);
  // group 0: steps 1..5 (no spike update), gamma/gate at s=5
  k_theta<<<32, 512, 0, stream>>>(ring, gamma, a_g, gateT, maskB, omega, W_ro,
                                  W_fb, 1, 5, 0);
  for (int k = 1; k < 40; ++k) {
    const unsigned short* mrd = (k & 1) ? maskA : maskB;  // k=1 reads zeros
    unsigned short* mwr = (k & 1) ? maskB : maskA;
    k_spike<<<NG, 512, 0, stream>>>(mrd, mwr, memD, gateT, W_rec, W_gate, rate,
                                    (k >= 10) ? 1 : 0);
    k_theta<<<32, 512, 0, stream>>>(ring, gamma, a_g, gateT, mwr, omega, W_ro,
                                    W_fb, 5 * k + 1, 5 * k + 5, 1);
  }
  k_cls<<<32, 256, 0, stream>>>(rate, W_cls, b_cls, (float*)d_out);
}

// Round 5
// 8491.167 us; speedup vs baseline: 1.6985x; 1.6985x over previous
//
#include <hip/hip_runtime.h>
#include <cstdint>
#include <cstddef>

#define BB 32
#define NN 256
#define PP 3072
#define NG 192   // pixel groups of 16
#define RING 16

// ---- init: gamma0 = tanh(x @ W_init) fp64, ring[0]=theta0, zero state ----
__global__ __launch_bounds__(256) void k_init(
    const float* __restrict__ x, const float* __restrict__ theta0,
    const float* __restrict__ W_init, double* __restrict__ ring,
    double* __restrict__ gamma_g, double* __restrict__ memD,
    double* __restrict__ a_g, float* __restrict__ rate,
    unsigned short* __restrict__ maskA, unsigned short* __restrict__ maskB,
    int* __restrict__ spk_cnt) {
  const int blk = blockIdx.x, tid = threadIdx.x;
  if (blk < BB) {
    __shared__ double xl[PP];  // 24 KB
    for (int i = tid; i < PP; i += 256) xl[i] = (double)x[(size_t)blk * PP + i];
    __syncthreads();
    double acc = 0.0;
#pragma unroll 4
    for (int p = 0; p < PP; ++p)
      acc += xl[p] * (double)W_init[(size_t)p * NN + tid];
    gamma_g[blk * NN + tid] = tanh(acc);
    ring[blk * NN + tid] = (double)theta0[blk * NN + tid];
    if (tid < 1 && blk < BB) spk_cnt[blk] = 0;
  } else {
    const int i0 = (blk - BB) * 256 + tid, st = (gridDim.x - BB) * 256;
    for (int i = i0; i < BB * PP; i += st) { memD[i] = 0.0; rate[i] = 0.f; }
    for (int i = i0; i < BB * NN; i += st) a_g[i] = 0.0;
    for (int i = i0; i < BB * NG; i += st) { maskA[i] = 0; maskB[i] = 0; }
  }
}

// ---- spike update (s = 5k+1), pure VALU fp64 ----
// gate matmul from LDS-staged operands; rec part via compact spike list
// (independent, unrollable loads). Semantics identical to round-4 PASS.
__global__ __launch_bounds__(512) void k_spike(
    const unsigned short* __restrict__ mask_rd,
    unsigned short* __restrict__ mask_wr, double* __restrict__ memD,
    const double* __restrict__ gateT, const float* __restrict__ W_rec,
    const float* __restrict__ W_gate, const unsigned short* __restrict__ spk_list,
    const int* __restrict__ spk_cnt, float* __restrict__ rate, int accum) {
  __shared__ double gl[NN * BB];   // 64 KB: gate [osc][batch]
  __shared__ float wgl[NN * 16];   // 16 KB: W_gate tile [osc][16 px]
  __shared__ int cnt_l[BB];
  const int g = blockIdx.x, j0 = g * 16, tid = threadIdx.x;
  for (int i = tid; i < NN * BB; i += 512) gl[i] = gateT[i];
  for (int i = tid; i < NN * 16; i += 512)
    wgl[i] = W_gate[(size_t)(i >> 4) * PP + j0 + (i & 15)];
  if (tid < BB) cnt_l[tid] = spk_cnt[tid];
  __syncthreads();

  const int pi = tid & 15, b = tid >> 4, p = j0 + pi;
  // gate part: dense K=256 fp64, pure LDS
  double vg = 0.0;
#pragma unroll 8
  for (int k = 0; k < NN; ++k) vg += gl[k * BB + b] * (double)wgl[k * 16 + pi];

  // rec part: compact list of active pixels (sorted, deterministic)
  double vr = 0.0;
  const unsigned short* lst = spk_list + (size_t)b * PP;
  const int cnt = cnt_l[b];
  int i = 0;
  for (; i + 4 <= cnt; i += 4) {
    const int r0 = lst[i], r1 = lst[i + 1], r2 = lst[i + 2], r3 = lst[i + 3];
    vr += (double)W_rec[(size_t)r0 * PP + p] + (double)W_rec[(size_t)r1 * PP + p] +
          (double)W_rec[(size_t)r2 * PP + p] + (double)W_rec[(size_t)r3 * PP + p];
  }
  for (; i < cnt; ++i) vr += (double)W_rec[(size_t)lst[i] * PP + p];

  const double cur = vg + 0.1 * vr;
  const double so = (double)((mask_rd[b * NG + g] >> pi) & 1);
  const size_t idx = (size_t)b * PP + p;
  const double mv = 0.9 * memD[idx] * (1.0 - so) + cur;
  const double sv = (mv - 1.0 > 0.0) ? 1.0 : 0.0;
  memD[idx] = mv;
  if (accum) rate[idx] += (float)sv;

  unsigned long long bal = __ballot(sv > 0.5);
  const int lane = tid & 63;
  const int bl = lane >> 4;
  const int wb = (tid >> 6) * 4;
  if ((lane & 15) == 0)
    mask_wr[(wb + bl) * NG + g] =
        (unsigned short)((bal >> (16 * bl)) & 0xFFFFull);
}

// ---- theta steps s0..s1 (fp64) + mask compaction + a = tanh(spk@W_fb)
//      + gamma/gate.  One block per batch, 512 threads. ----
__global__ __launch_bounds__(512) void k_theta(
    double* __restrict__ ring, double* __restrict__ gamma_g,
    double* __restrict__ a_g, double* __restrict__ gateT,
    const unsigned short* __restrict__ spk_mask,
    unsigned short* __restrict__ spk_list, int* __restrict__ spk_cnt,
    const float* __restrict__ omega, const float* __restrict__ W_ro,
    const float* __restrict__ W_fb, int s0, int s1, int has_spike) {
  const int b = blockIdx.x, tid = threadIdx.x;
  const int j = tid & 255, half = tid >> 8;
  __shared__ double acc_half[256];
  __shared__ double red[32];
  __shared__ double th[256];
  __shared__ unsigned short m_l[NG];
  __shared__ int pc[NG], sc[NG];
  __shared__ unsigned short list_l[PP];  // 6 KB

  // --- compact the new spike mask into a sorted pixel list ---
  int total = 0;
  if (has_spike) {
    if (tid < NG) {
      m_l[tid] = spk_mask[b * NG + tid];
      pc[tid] = __popc((unsigned int)m_l[tid]);
      sc[tid] = pc[tid];
    }
    __syncthreads();
    for (int d = 1; d < NG; d <<= 1) {
      int v = 0;
      if (tid < NG) v = sc[tid] + ((tid >= d) ? sc[tid - d] : 0);
      __syncthreads();
      if (tid < NG) sc[tid] = v;
      __syncthreads();
    }
    total = sc[NG - 1];
    if (tid < NG) {
      int off = sc[tid] - pc[tid];
      unsigned int m = m_l[tid];
      while (m) {
        int bit = __builtin_ctz(m);
        m &= m - 1;
        list_l[off++] = (unsigned short)(tid * 16 + bit);
      }
    }
    __syncthreads();
    for (int i = tid; i < total; i += 512) spk_list[(size_t)b * PP + i] = list_l[i];
    if (tid == 0) spk_cnt[b] = total;
  }

  // --- a = tanh(spk @ W_fb) over the compact list ---
  double acc = 0.0;
  if (has_spike) {
    for (int i = half; i < total; i += 2)
      acc += (double)W_fb[(size_t)list_l[i] * NN + j];
  }
  if (half) acc_half[j] = acc;
  __syncthreads();
  double new_a = 0.0;
  if (!half && has_spike) new_a = tanh(acc + acc_half[j]);

  double t = 0.0, aj = 0.0, gm = 0.0, om = 0.0;
  if (tid < 256) {
    t = ring[((s0 - 1) & (RING - 1)) * BB * NN + b * NN + j];
    aj = a_g[b * NN + j];
    gm = gamma_g[b * NN + j];
    om = (double)omega[j];
  }
  const int lane = tid & 63, wid = tid >> 6;
  for (int s = s0; s <= s1; ++s) {
    // step s0 (=5k+1) uses the OLD a (ref: spike update follows theta update)
    if (tid < 256 && has_spike && s == s0 + 1) {
      aj = new_a;
      a_g[b * NN + j] = aj;
    }
    double sn = 0.0, cs = 0.0;
    if (tid < 256) sincos(t, &sn, &cs);
    double r0 = sn, r1 = cs, r2 = aj * sn, r3 = aj * cs;
#pragma unroll
    for (int o = 32; o; o >>= 1) {
      r0 += __shfl_down(r0, o);
      r1 += __shfl_down(r1, o);
      r2 += __shfl_down(r2, o);
      r3 += __shfl_down(r3, o);
    }
    if (lane == 0) {
      red[wid * 4 + 0] = r0;
      red[wid * 4 + 1] = r1;
      red[wid * 4 + 2] = r2;
      red[wid * 4 + 3] = r3;
    }
    __syncthreads();
    double S = red[0] + red[4] + red[8] + red[12];
    double C = red[1] + red[5] + red[9] + red[13];
    double AS = red[2] + red[6] + red[10] + red[14];
    double AC = red[3] + red[7] + red[11] + red[15];
    __syncthreads();
    if (tid < 256) {
      double base = cs * S - sn * C;
      double wgt = 0.5 * (cs * aj * AS - sn * aj * AC);
      double dth = om + (1.0 / 256.0) * (base + wgt) + 0.5 * gm;
      t = t + 0.1 * dth;
      ring[(s & (RING - 1)) * BB * NN + b * NN + j] = t;
    }
  }
  if (tid < 256) th[j] = t;
  __syncthreads();
  if (tid < 256) {
    double acc2 = 0.0;
#pragma unroll 4
    for (int i = 0; i < NN; ++i) acc2 += th[i] * (double)W_ro[i * NN + j];
    double gnew = tanh(acc2);
    gamma_g[b * NN + j] = gnew;
    int sd = s1 - 11;
    if (sd < 0) sd = 0;
    double dly = ring[(sd & (RING - 1)) * BB * NN + b * NN + j];
    double gt = gnew * 0.5 * (1.0 + cos(t - dly));
    gateT[j * BB + b] = gt;  // [osc][batch]
  }
}

// ---- classifier: logits = (rate/30) @ W_cls + b_cls, fp64 accumulate ----
__global__ __launch_bounds__(256) void k_cls(const float* __restrict__ rate,
                                             const float* __restrict__ Wcls,
                                             const float* __restrict__ bcls,
                                             float* __restrict__ out) {
  const int b = blockIdx.x, t = threadIdx.x;
  double acc[10];
#pragma unroll
  for (int c = 0; c < 10; ++c) acc[c] = 0.0;
  for (int p = t; p < PP; p += 256) {
    double r = (double)rate[(size_t)b * PP + p] / 30.0;
#pragma unroll
    for (int c = 0; c < 10; ++c) acc[c] += r * (double)Wcls[(size_t)p * 10 + c];
  }
  __shared__ double sh[10][256];  // 20 KB
#pragma unroll
  for (int c = 0; c < 10; ++c) sh[c][t] = acc[c];
  __syncthreads();
  for (int off = 128; off; off >>= 1) {
    if (t < off)
#pragma unroll
      for (int c = 0; c < 10; ++c) sh[c][t] += sh[c][t + off];
    __syncthreads();
  }
  if (t < 10) out[b * 10 + t] = (float)(sh[t][0] + (double)bcls[t]);
}

extern "C" void kernel_launch(void* const* d_in, const int* in_sizes, int n_in,
                              void* d_out, int out_size, void* d_ws,
                              size_t ws_size, hipStream_t stream) {
  const float* x = (const float*)d_in[0];
  const float* theta0 = (const float*)d_in[1];
  const float* W_init = (const float*)d_in[2];
  const float* omega = (const float*)d_in[3];
  const float* W_ro = (const float*)d_in[4];
  const float* W_gate = (const float*)d_in[5];
  const float* W_rec = (const float*)d_in[6];
  const float* W_fb = (const float*)d_in[7];
  const float* W_cls = (const float*)d_in[8];
  const float* b_cls = (const float*)d_in[9];

  char* w = (char*)d_ws;
  size_t off = 0;
  auto alloc = [&](size_t sz) -> void* {
    void* p = w + off;
    off = (off + sz + 255) & ~(size_t)255;
    return p;
  };
  double* ring = (double*)alloc((size_t)RING * BB * NN * 8);  // theta ring
  double* gamma = (double*)alloc((size_t)BB * NN * 8);
  double* a_g = (double*)alloc((size_t)BB * NN * 8);
  double* gateT = (double*)alloc((size_t)BB * NN * 8);
  double* memD = (double*)alloc((size_t)BB * PP * 8);
  float* rate = (float*)alloc((size_t)BB * PP * 4);
  unsigned short* maskA = (unsigned short*)alloc((size_t)BB * NG * 2);
  unsigned short* maskB = (unsigned short*)alloc((size_t)BB * NG * 2);
  unsigned short* spk_list = (unsigned short*)alloc((size_t)BB * PP * 2);
  int* spk_cnt = (int*)alloc((size_t)BB * 4);
  // total ~2.5 MB of ws

  k_init<<<224, 256, 0, stream>>>(x, theta0, W_init, ring, gamma, memD, a_g,
                                  rate, maskA, maskB, spk_cnt);
  // group 0: steps 1..5 (no spike update), gamma/gate at s=5
  k_theta<<<32, 512, 0, stream>>>(ring, gamma, a_g, gateT, maskB, spk_list,
                                  spk_cnt, omega, W_ro, W_fb, 1, 5, 0);
  for (int k = 1; k < 40; ++k) {
    const unsigned short* mrd = (k & 1) ? maskA : maskB;  // k=1 reads zeros
    unsigned short* mwr = (k & 1) ? maskB : maskA;
    k_spike<<<NG, 512, 0, stream>>>(mrd, mwr, memD, gateT, W_rec, W_gate,
                                    spk_list, spk_cnt, rate, (k >= 10) ? 1 : 0);
    k_theta<<<32, 512, 0, stream>>>(ring, gamma, a_g, gateT, mwr, spk_list,
                                    spk_cnt, omega, W_ro, W_fb, 5 * k + 1,
                                    5 * k + 5, 1);
  }
  k_cls<<<32, 256, 0, stream>>>(rate, W_cls, b_cls, (float*)d_out);
}

// Round 6
// 4009.618 us; speedup vs baseline: 3.5969x; 2.1177x over previous
//
#include <hip/hip_runtime.h>
#include <cstdint>
#include <cstddef>

#define BB 32
#define NN 256
#define PP 3072
#define NG 192   // pixel groups of 16
#define RING 16

typedef short v8us __attribute__((ext_vector_type(8)));

// ---- init: gamma0 = tanh(x @ W_init) fp64, ring[0]=theta0, zero state ----
__global__ __launch_bounds__(256) void k_init(
    const float* __restrict__ x, const float* __restrict__ theta0,
    const float* __restrict__ W_init, double* __restrict__ ring,
    double* __restrict__ gamma_g, double* __restrict__ memD,
    double* __restrict__ a_g, float* __restrict__ rate,
    unsigned short* __restrict__ maskA, unsigned short* __restrict__ maskB,
    int* __restrict__ spk_cnt) {
  const int blk = blockIdx.x, tid = threadIdx.x;
  if (blk < BB) {
    __shared__ double xl[PP];  // 24 KB
    for (int i = tid; i < PP; i += 256) xl[i] = (double)x[(size_t)blk * PP + i];
    __syncthreads();
    // 8 independent accumulators: fp64 reassociation is trajectory-safe
    double a0 = 0, a1 = 0, a2 = 0, a3 = 0, a4 = 0, a5 = 0, a6 = 0, a7 = 0;
    const float* wp = W_init + tid;
    for (int p = 0; p < PP; p += 8) {
      a0 += xl[p + 0] * (double)wp[(size_t)(p + 0) * NN];
      a1 += xl[p + 1] * (double)wp[(size_t)(p + 1) * NN];
      a2 += xl[p + 2] * (double)wp[(size_t)(p + 2) * NN];
      a3 += xl[p + 3] * (double)wp[(size_t)(p + 3) * NN];
      a4 += xl[p + 4] * (double)wp[(size_t)(p + 4) * NN];
      a5 += xl[p + 5] * (double)wp[(size_t)(p + 5) * NN];
      a6 += xl[p + 6] * (double)wp[(size_t)(p + 6) * NN];
      a7 += xl[p + 7] * (double)wp[(size_t)(p + 7) * NN];
    }
    double acc = ((a0 + a1) + (a2 + a3)) + ((a4 + a5) + (a6 + a7));
    gamma_g[blk * NN + tid] = tanh(acc);
    ring[blk * NN + tid] = (double)theta0[blk * NN + tid];
    if (tid < 1) spk_cnt[blk] = 0;
  } else {
    const int i0 = (blk - BB) * 256 + tid, st = (gridDim.x - BB) * 256;
    for (int i = i0; i < BB * PP; i += st) { memD[i] = 0.0; rate[i] = 0.f; }
    for (int i = i0; i < BB * NN; i += st) a_g[i] = 0.0;
    for (int i = i0; i < BB * NG; i += st) { maskA[i] = 0; maskB[i] = 0; }
  }
}

// ---- spike update (s = 5k+1), pure VALU fp64, 8-way MLP ----
__global__ __launch_bounds__(512) void k_spike(
    const unsigned short* __restrict__ mask_rd,
    unsigned short* __restrict__ mask_wr, double* __restrict__ memD,
    const double* __restrict__ gateT, const float* __restrict__ W_rec,
    const float* __restrict__ W_gate, const unsigned short* __restrict__ spk_list,
    const int* __restrict__ spk_cnt, float* __restrict__ rate, int accum) {
  __shared__ double gl[NN * BB];   // 64 KB: gate [osc][batch]
  __shared__ float wgl[NN * 16];   // 16 KB: W_gate tile [osc][16 px]
  __shared__ int cnt_l[BB];
  const int g = blockIdx.x, j0 = g * 16, tid = threadIdx.x;
  for (int i = tid; i < NN * BB; i += 512) gl[i] = gateT[i];
  for (int i = tid; i < NN * 16; i += 512)
    wgl[i] = W_gate[(size_t)(i >> 4) * PP + j0 + (i & 15)];
  if (tid < BB) cnt_l[tid] = spk_cnt[tid];
  __syncthreads();

  const int pi = tid & 15, b = tid >> 4, p = j0 + pi;
  // gate part: dense K=256 fp64, pure LDS, 4 accumulators
  double g0 = 0, g1 = 0, g2 = 0, g3 = 0;
  for (int k = 0; k < NN; k += 4) {
    g0 += gl[(k + 0) * BB + b] * (double)wgl[(k + 0) * 16 + pi];
    g1 += gl[(k + 1) * BB + b] * (double)wgl[(k + 1) * 16 + pi];
    g2 += gl[(k + 2) * BB + b] * (double)wgl[(k + 2) * 16 + pi];
    g3 += gl[(k + 3) * BB + b] * (double)wgl[(k + 3) * 16 + pi];
  }
  const double vg = (g0 + g1) + (g2 + g3);

  // rec part: compact active-pixel list, 8 independent load+acc streams
  double v0 = 0, v1 = 0, v2 = 0, v3 = 0, v4 = 0, v5 = 0, v6 = 0, v7 = 0;
  const unsigned short* lst = spk_list + (size_t)b * PP;
  const int cnt = cnt_l[b];
  int i = 0;
  for (; i + 8 <= cnt; i += 8) {
    v8us r = *reinterpret_cast<const v8us*>(lst + i);  // 16B aligned
    v0 += (double)W_rec[(size_t)(unsigned short)r[0] * PP + p];
    v1 += (double)W_rec[(size_t)(unsigned short)r[1] * PP + p];
    v2 += (double)W_rec[(size_t)(unsigned short)r[2] * PP + p];
    v3 += (double)W_rec[(size_t)(unsigned short)r[3] * PP + p];
    v4 += (double)W_rec[(size_t)(unsigned short)r[4] * PP + p];
    v5 += (double)W_rec[(size_t)(unsigned short)r[5] * PP + p];
    v6 += (double)W_rec[(size_t)(unsigned short)r[6] * PP + p];
    v7 += (double)W_rec[(size_t)(unsigned short)r[7] * PP + p];
  }
  double vr = ((v0 + v1) + (v2 + v3)) + ((v4 + v5) + (v6 + v7));
  for (; i < cnt; ++i) vr += (double)W_rec[(size_t)lst[i] * PP + p];

  const double cur = vg + 0.1 * vr;
  const double so = (double)((mask_rd[b * NG + g] >> pi) & 1);
  const size_t idx = (size_t)b * PP + p;
  const double mv = 0.9 * memD[idx] * (1.0 - so) + cur;
  const double sv = (mv - 1.0 > 0.0) ? 1.0 : 0.0;
  memD[idx] = mv;
  if (accum) rate[idx] += (float)sv;

  unsigned long long bal = __ballot(sv > 0.5);
  const int lane = tid & 63;
  const int bl = lane >> 4;
  const int wb = (tid >> 6) * 4;
  if ((lane & 15) == 0)
    mask_wr[(wb + bl) * NG + g] =
        (unsigned short)((bal >> (16 * bl)) & 0xFFFFull);
}

// ---- theta steps s0..s1 (fp64) + mask compaction + a = tanh(spk@W_fb)
//      + gamma/gate.  One block per batch, 512 threads. ----
__global__ __launch_bounds__(512) void k_theta(
    double* __restrict__ ring, double* __restrict__ gamma_g,
    double* __restrict__ a_g, double* __restrict__ gateT,
    const unsigned short* __restrict__ spk_mask,
    unsigned short* __restrict__ spk_list, int* __restrict__ spk_cnt,
    const float* __restrict__ omega, const float* __restrict__ W_ro,
    const float* __restrict__ W_fb, int s0, int s1, int has_spike) {
  const int b = blockIdx.x, tid = threadIdx.x;
  const int j = tid & 255, half = tid >> 8;
  __shared__ double acc_half[256];
  __shared__ double red[32];
  __shared__ double th[256];
  __shared__ unsigned short m_l[NG];
  __shared__ int pc[NG], sc[NG];
  __shared__ unsigned short list_l[PP];  // 6 KB

  // --- compact the new spike mask into a sorted pixel list ---
  int total = 0;
  if (has_spike) {
    if (tid < NG) {
      m_l[tid] = spk_mask[b * NG + tid];
      pc[tid] = __popc((unsigned int)m_l[tid]);
      sc[tid] = pc[tid];
    }
    __syncthreads();
    for (int d = 1; d < NG; d <<= 1) {
      int v = 0;
      if (tid < NG) v = sc[tid] + ((tid >= d) ? sc[tid - d] : 0);
      __syncthreads();
      if (tid < NG) sc[tid] = v;
      __syncthreads();
    }
    total = sc[NG - 1];
    if (tid < NG) {
      int off = sc[tid] - pc[tid];
      unsigned int m = m_l[tid];
      while (m) {
        int bit = __builtin_ctz(m);
        m &= m - 1;
        list_l[off++] = (unsigned short)(tid * 16 + bit);
      }
    }
    __syncthreads();
    for (int i = tid; i < total; i += 512) spk_list[(size_t)b * PP + i] = list_l[i];
    if (tid == 0) spk_cnt[b] = total;
  }

  // --- a = tanh(spk @ W_fb): 8 independent streams over the compact list ---
  double acc = 0.0;
  if (has_spike) {
    double c0 = 0, c1 = 0, c2 = 0, c3 = 0, c4 = 0, c5 = 0, c6 = 0, c7 = 0;
    int i = half;
    for (; i + 16 <= total; i += 16) {
      c0 += (double)W_fb[(size_t)list_l[i + 0] * NN + j];
      c1 += (double)W_fb[(size_t)list_l[i + 2] * NN + j];
      c2 += (double)W_fb[(size_t)list_l[i + 4] * NN + j];
      c3 += (double)W_fb[(size_t)list_l[i + 6] * NN + j];
      c4 += (double)W_fb[(size_t)list_l[i + 8] * NN + j];
      c5 += (double)W_fb[(size_t)list_l[i + 10] * NN + j];
      c6 += (double)W_fb[(size_t)list_l[i + 12] * NN + j];
      c7 += (double)W_fb[(size_t)list_l[i + 14] * NN + j];
    }
    acc = ((c0 + c1) + (c2 + c3)) + ((c4 + c5) + (c6 + c7));
    for (; i < total; i += 2) acc += (double)W_fb[(size_t)list_l[i] * NN + j];
  }
  if (half) acc_half[j] = acc;
  __syncthreads();
  double new_a = 0.0;
  if (!half && has_spike) new_a = tanh(acc + acc_half[j]);

  double t = 0.0, aj = 0.0, gm = 0.0, om = 0.0;
  if (tid < 256) {
    t = ring[((s0 - 1) & (RING - 1)) * BB * NN + b * NN + j];
    aj = a_g[b * NN + j];
    gm = gamma_g[b * NN + j];
    om = (double)omega[j];
  }
  const int lane = tid & 63, wid = tid >> 6;
  for (int s = s0; s <= s1; ++s) {
    // step s0 (=5k+1) uses the OLD a (ref: spike update follows theta update)
    if (tid < 256 && has_spike && s == s0 + 1) {
      aj = new_a;
      a_g[b * NN + j] = aj;
    }
    double sn = 0.0, cs = 0.0;
    if (tid < 256) sincos(t, &sn, &cs);
    double r0 = sn, r1 = cs, r2 = aj * sn, r3 = aj * cs;
#pragma unroll
    for (int o = 32; o; o >>= 1) {
      r0 += __shfl_down(r0, o);
      r1 += __shfl_down(r1, o);
      r2 += __shfl_down(r2, o);
      r3 += __shfl_down(r3, o);
    }
    if (lane == 0) {
      red[wid * 4 + 0] = r0;
      red[wid * 4 + 1] = r1;
      red[wid * 4 + 2] = r2;
      red[wid * 4 + 3] = r3;
    }
    __syncthreads();
    double S = red[0] + red[4] + red[8] + red[12];
    double C = red[1] + red[5] + red[9] + red[13];
    double AS = red[2] + red[6] + red[10] + red[14];
    double AC = red[3] + red[7] + red[11] + red[15];
    __syncthreads();
    if (tid < 256) {
      double base = cs * S - sn * C;
      double wgt = 0.5 * (cs * aj * AS - sn * aj * AC);
      double dth = om + (1.0 / 256.0) * (base + wgt) + 0.5 * gm;
      t = t + 0.1 * dth;
      ring[(s & (RING - 1)) * BB * NN + b * NN + j] = t;
    }
  }
  if (tid < 256) th[j] = t;
  __syncthreads();
  if (tid < 256) {
    // gamma = tanh(theta @ W_ro): 8 independent streams
    double c0 = 0, c1 = 0, c2 = 0, c3 = 0, c4 = 0, c5 = 0, c6 = 0, c7 = 0;
    const float* wp = W_ro + j;
    for (int i = 0; i < NN; i += 8) {
      c0 += th[i + 0] * (double)wp[(size_t)(i + 0) * NN];
      c1 += th[i + 1] * (double)wp[(size_t)(i + 1) * NN];
      c2 += th[i + 2] * (double)wp[(size_t)(i + 2) * NN];
      c3 += th[i + 3] * (double)wp[(size_t)(i + 3) * NN];
      c4 += th[i + 4] * (double)wp[(size_t)(i + 4) * NN];
      c5 += th[i + 5] * (double)wp[(size_t)(i + 5) * NN];
      c6 += th[i + 6] * (double)wp[(size_t)(i + 6) * NN];
      c7 += th[i + 7] * (double)wp[(size_t)(i + 7) * NN];
    }
    double acc2 = ((c0 + c1) + (c2 + c3)) + ((c4 + c5) + (c6 + c7));
    double gnew = tanh(acc2);
    gamma_g[b * NN + j] = gnew;
    int sd = s1 - 11;
    if (sd < 0) sd = 0;
    double dly = ring[(sd & (RING - 1)) * BB * NN + b * NN + j];
    double gt = gnew * 0.5 * (1.0 + cos(t - dly));
    gateT[j * BB + b] = gt;  // [osc][batch]
  }
}

// ---- classifier: logits = (rate/30) @ W_cls + b_cls, fp64 accumulate ----
__global__ __launch_bounds__(256) void k_cls(const float* __restrict__ rate,
                                             const float* __restrict__ Wcls,
                                             const float* __restrict__ bcls,
                                             float* __restrict__ out) {
  const int b = blockIdx.x, t = threadIdx.x;
  double acc[10];
#pragma unroll
  for (int c = 0; c < 10; ++c) acc[c] = 0.0;
  for (int p = t; p < PP; p += 256) {
    double r = (double)rate[(size_t)b * PP + p] / 30.0;
#pragma unroll
    for (int c = 0; c < 10; ++c) acc[c] += r * (double)Wcls[(size_t)p * 10 + c];
  }
  __shared__ double sh[10][256];  // 20 KB
#pragma unroll
  for (int c = 0; c < 10; ++c) sh[c][t] = acc[c];
  __syncthreads();
  for (int off = 128; off; off >>= 1) {
    if (t < off)
#pragma unroll
      for (int c = 0; c < 10; ++c) sh[c][t] += sh[c][t + off];
    __syncthreads();
  }
  if (t < 10) out[b * 10 + t] = (float)(sh[t][0] + (double)bcls[t]);
}

extern "C" void kernel_launch(void* const* d_in, const int* in_sizes, int n_in,
                              void* d_out, int out_size, void* d_ws,
                              size_t ws_size, hipStream_t stream) {
  const float* x = (const float*)d_in[0];
  const float* theta0 = (const float*)d_in[1];
  const float* W_init = (const float*)d_in[2];
  const float* omega = (const float*)d_in[3];
  const float* W_ro = (const float*)d_in[4];
  const float* W_gate = (const float*)d_in[5];
  const float* W_rec = (const float*)d_in[6];
  const float* W_fb = (const float*)d_in[7];
  const float* W_cls = (const float*)d_in[8];
  const float* b_cls = (const float*)d_in[9];

  char* w = (char*)d_ws;
  size_t off = 0;
  auto alloc = [&](size_t sz) -> void* {
    void* p = w + off;
    off = (off + sz + 255) & ~(size_t)255;
    return p;
  };
  double* ring = (double*)alloc((size_t)RING * BB * NN * 8);  // theta ring
  double* gamma = (double*)alloc((size_t)BB * NN * 8);
  double* a_g = (double*)alloc((size_t)BB * NN * 8);
  double* gateT = (double*)alloc((size_t)BB * NN * 8);
  double* memD = (double*)alloc((size_t)BB * PP * 8);
  float* rate = (float*)alloc((size_t)BB * PP * 4);
  unsigned short* maskA = (unsigned short*)alloc((size_t)BB * NG * 2);
  unsigned short* maskB = (unsigned short*)alloc((size_t)BB * NG * 2);
  unsigned short* spk_list = (unsigned short*)alloc((size_t)BB * PP * 2);
  int* spk_cnt = (int*)alloc((size_t)BB * 4);
  // total ~2.5 MB of ws

  k_init<<<224, 256, 0, stream>>>(x, theta0, W_init, ring, gamma, memD, a_g,
                                  rate, maskA, maskB, spk_cnt);
  // group 0: steps 1..5 (no spike update), gamma/gate at s=5
  k_theta<<<32, 512, 0, stream>>>(ring, gamma, a_g, gateT, maskB, spk_list,
                                  spk_cnt, omega, W_ro, W_fb, 1, 5, 0);
  for (int k = 1; k < 40; ++k) {
    const unsigned short* mrd = (k & 1) ? maskA : maskB;  // k=1 reads zeros
    unsigned short* mwr = (k & 1) ? maskB : maskA;
    k_spike<<<NG, 512, 0, stream>>>(mrd, mwr, memD, gateT, W_rec, W_gate,
                                    spk_list, spk_cnt, rate, (k >= 10) ? 1 : 0);
    k_theta<<<32, 512, 0, stream>>>(ring, gamma, a_g, gateT, mwr, spk_list,
                                    spk_cnt, omega, W_ro, W_fb, 5 * k + 1,
                                    5 * k + 5, 1);
  }
  k_cls<<<32, 256, 0, stream>>>(rate, W_cls, b_cls, (float*)d_out);
}